// Round 1
// baseline (431.622 us; speedup 1.0000x reference)
//
#include <hip/hip_runtime.h>

// Deformable Conv2d given offsets — MI355X
// Shapes (fixed by setup_inputs):
//   x:      [B=4, Cin=64, H=256, W=256] f32
//   offset: [B, 2, G*KK=72, H, W] f32   (tap axis FLIPPED in reference)
//   mask:   [B, 72, H, W] f32 (sigmoid applied)
//   weight: [OC=64, Cpg=8, 3, 3] f32
//   bias:   [OC] f32
//   out:    [B, 64, H, W] f32

#define KSZ 3
#define PAD 1

static constexpr int B   = 4;
static constexpr int Cin = 64;
static constexpr int H   = 256;
static constexpr int W   = 256;
static constexpr int G   = 8;
static constexpr int OC  = 64;
static constexpr int KK  = KSZ * KSZ;      // 9
static constexpr int Cpg = Cin / G;        // 8
static constexpr int OPG = OC / G;         // 8
static constexpr int HW  = H * W;          // 65536

__global__ __launch_bounds__(256) void dcn_kernel(
    const float* __restrict__ x,
    const float* __restrict__ offset,
    const float* __restrict__ mask,
    const float* __restrict__ weight,
    const float* __restrict__ bias,
    float* __restrict__ out)
{
    const int h = blockIdx.x;
    const int g = blockIdx.y;
    const int b = blockIdx.z;
    const int w = threadIdx.x;

    // Stage this group's weights in LDS as [t][c][d] (576 floats = 2.3 KB).
    // All lanes read the same address in the inner loop -> LDS broadcast.
    __shared__ float wlds[KK * Cpg * OPG];
    for (int i = threadIdx.x; i < KK * Cpg * OPG; i += blockDim.x) {
        const int t = i / (Cpg * OPG);
        const int r = i - t * (Cpg * OPG);
        const int c = r / OPG;
        const int d = r - c * OPG;
        wlds[i] = weight[((g * OPG + d) * Cpg + c) * KK + t];
    }
    __syncthreads();

    float acc[OPG];
#pragma unroll
    for (int d = 0; d < OPG; ++d) acc[d] = 0.0f;

    const float* xbase = x + (size_t)(b * Cin + g * Cpg) * HW;
    const int pix = h * W + w;

#pragma unroll
    for (int t = 0; t < KK; ++t) {
        const int ki = t / KSZ;
        const int kj = t - ki * KSZ;
        // reference: off = flip(offset, axis=2) -> channel 71-(g*9+t)
        const int idx0 = G * KK - 1 - (g * KK + t);
        const float dy = offset[((size_t)(b * 2 + 0) * (G * KK) + idx0) * HW + pix];
        const float dx = offset[((size_t)(b * 2 + 1) * (G * KK) + idx0) * HW + pix];
        const float mv = mask[((size_t)b * (G * KK) + g * KK + t) * HW + pix];
        const float m = 1.0f / (1.0f + __expf(-mv));

        const float py = (float)(h - PAD + ki) + dy;
        const float px = (float)(w - PAD + kj) + dx;
        const float y0f = floorf(py);
        const float x0f = floorf(px);
        const float wy = py - y0f;
        const float wx = px - x0f;
        const int y0 = (int)y0f, x0 = (int)x0f;
        const int y1 = y0 + 1,   x1 = x0 + 1;

        const bool vy0 = (y0 >= 0) & (y0 < H);
        const bool vy1 = (y1 >= 0) & (y1 < H);
        const bool vx0 = (x0 >= 0) & (x0 < W);
        const bool vx1 = (x1 >= 0) & (x1 < W);

        const int yc0 = min(max(y0, 0), H - 1);
        const int yc1 = min(max(y1, 0), H - 1);
        const int xc0 = min(max(x0, 0), W - 1);
        const int xc1 = min(max(x1, 0), W - 1);

        // fold validity and sigmoid(mask) into the 4 corner weights
        float w00 = (1.0f - wy) * (1.0f - wx) * m;
        float w01 = (1.0f - wy) * wx * m;
        float w10 = wy * (1.0f - wx) * m;
        float w11 = wy * wx * m;
        w00 = (vy0 & vx0) ? w00 : 0.0f;
        w01 = (vy0 & vx1) ? w01 : 0.0f;
        w10 = (vy1 & vx0) ? w10 : 0.0f;
        w11 = (vy1 & vx1) ? w11 : 0.0f;

        const int o00 = yc0 * W + xc0;
        const int o01 = yc0 * W + xc1;
        const int o10 = yc1 * W + xc0;
        const int o11 = yc1 * W + xc1;

        const float* wt = &wlds[t * Cpg * OPG];
#pragma unroll
        for (int c = 0; c < Cpg; ++c) {
            const float* p = xbase + (size_t)c * HW;
            const float s = w00 * p[o00] + w01 * p[o01] + w10 * p[o10] + w11 * p[o11];
            // two ds_read_b128 broadcast reads of the weight row
            const float4 wv0 = *reinterpret_cast<const float4*>(&wt[c * OPG]);
            const float4 wv1 = *reinterpret_cast<const float4*>(&wt[c * OPG + 4]);
            acc[0] += s * wv0.x;
            acc[1] += s * wv0.y;
            acc[2] += s * wv0.z;
            acc[3] += s * wv0.w;
            acc[4] += s * wv1.x;
            acc[5] += s * wv1.y;
            acc[6] += s * wv1.z;
            acc[7] += s * wv1.w;
        }
    }

    float* ob = out + (size_t)(b * OC + g * OPG) * HW + pix;
#pragma unroll
    for (int d = 0; d < OPG; ++d) {
        ob[(size_t)d * HW] = acc[d] + bias[g * OPG + d];
    }
}

extern "C" void kernel_launch(void* const* d_in, const int* in_sizes, int n_in,
                              void* d_out, int out_size, void* d_ws, size_t ws_size,
                              hipStream_t stream) {
    const float* x      = (const float*)d_in[0];
    const float* offset = (const float*)d_in[1];
    const float* mask   = (const float*)d_in[2];
    const float* weight = (const float*)d_in[3];
    const float* bias   = (const float*)d_in[4];
    float* out = (float*)d_out;

    dim3 grid(H, G, B);
    dim3 block(W);
    dcn_kernel<<<grid, block, 0, stream>>>(x, offset, mask, weight, bias, out);
}

// Round 2
// 313.322 us; speedup vs baseline: 1.3776x; 1.3776x over previous
//
#include <hip/hip_runtime.h>

// Deformable Conv2d given offsets — MI355X, round 2
// Key change vs round 1: pre-transpose x to channels-last per group so each
// bilinear corner gather is 2x global_load_dwordx4 (32B of useful data) instead
// of 8 scattered 4B loads. 8x fewer vector-mem instructions on the gather path.

#define KSZ 3
#define PAD 1

static constexpr int B   = 4;
static constexpr int Cin = 64;
static constexpr int H   = 256;
static constexpr int W   = 256;
static constexpr int G   = 8;
static constexpr int OC  = 64;
static constexpr int KK  = KSZ * KSZ;      // 9
static constexpr int Cpg = Cin / G;        // 8
static constexpr int OPG = OC / G;         // 8
static constexpr int HW  = H * W;          // 65536

// ---- transpose: x [B,Cin,H,W] -> xt [B,G,H,W,Cpg] ----
__global__ __launch_bounds__(256) void transpose_kernel(
    const float* __restrict__ x, float* __restrict__ xt)
{
    const int h = blockIdx.x;
    const int g = blockIdx.y;
    const int b = blockIdx.z;
    const int w = threadIdx.x;
    const int pix = h * W + w;

    const float* src = x + (size_t)(b * Cin + g * Cpg) * HW + pix;
    float v[Cpg];
#pragma unroll
    for (int c = 0; c < Cpg; ++c) v[c] = src[(size_t)c * HW];  // coalesced per c

    float* dst = xt + ((size_t)(b * G + g) * HW + pix) * Cpg;  // 32B contiguous per lane
    float4* d4 = reinterpret_cast<float4*>(dst);
    d4[0] = make_float4(v[0], v[1], v[2], v[3]);
    d4[1] = make_float4(v[4], v[5], v[6], v[7]);
}

// ---- main kernel: channels-last gathers ----
__global__ __launch_bounds__(256) void dcn_kernel(
    const float* __restrict__ xt,
    const float* __restrict__ offset,
    const float* __restrict__ mask,
    const float* __restrict__ weight,
    const float* __restrict__ bias,
    float* __restrict__ out)
{
    const int h = blockIdx.x;
    const int g = blockIdx.y;
    const int b = blockIdx.z;
    const int w = threadIdx.x;

    // Stage this group's weights in LDS as [t][c][d]; inner reads are broadcast.
    __shared__ float wlds[KK * Cpg * OPG];
    for (int i = threadIdx.x; i < KK * Cpg * OPG; i += blockDim.x) {
        const int t = i / (Cpg * OPG);
        const int r = i - t * (Cpg * OPG);
        const int c = r / OPG;
        const int d = r - c * OPG;
        wlds[i] = weight[((g * OPG + d) * Cpg + c) * KK + t];
    }
    __syncthreads();

    float acc[OPG];
#pragma unroll
    for (int d = 0; d < OPG; ++d) acc[d] = 0.0f;

    const float* xb = xt + (size_t)(b * G + g) * HW * Cpg;
    const int pix = h * W + w;

#pragma unroll
    for (int t = 0; t < KK; ++t) {
        const int ki = t / KSZ;
        const int kj = t - ki * KSZ;
        // reference flips the (group,tap) axis: channel 71-(g*9+t)
        const int idx0 = G * KK - 1 - (g * KK + t);
        const float dy = offset[((size_t)(b * 2 + 0) * (G * KK) + idx0) * HW + pix];
        const float dx = offset[((size_t)(b * 2 + 1) * (G * KK) + idx0) * HW + pix];
        const float mv = mask[((size_t)b * (G * KK) + g * KK + t) * HW + pix];
        const float m = 1.0f / (1.0f + __expf(-mv));

        const float py = (float)(h - PAD + ki) + dy;
        const float px = (float)(w - PAD + kj) + dx;
        const float y0f = floorf(py);
        const float x0f = floorf(px);
        const float wy = py - y0f;
        const float wx = px - x0f;
        const int y0 = (int)y0f, x0 = (int)x0f;
        const int y1 = y0 + 1,   x1 = x0 + 1;

        const bool vy0 = (y0 >= 0) & (y0 < H);
        const bool vy1 = (y1 >= 0) & (y1 < H);
        const bool vx0 = (x0 >= 0) & (x0 < W);
        const bool vx1 = (x1 >= 0) & (x1 < W);

        const int yc0 = min(max(y0, 0), H - 1);
        const int yc1 = min(max(y1, 0), H - 1);
        const int xc0 = min(max(x0, 0), W - 1);
        const int xc1 = min(max(x1, 0), W - 1);

        float w00 = (1.0f - wy) * (1.0f - wx) * m;
        float w01 = (1.0f - wy) * wx * m;
        float w10 = wy * (1.0f - wx) * m;
        float w11 = wy * wx * m;
        w00 = (vy0 & vx0) ? w00 : 0.0f;
        w01 = (vy0 & vx1) ? w01 : 0.0f;
        w10 = (vy1 & vx0) ? w10 : 0.0f;
        w11 = (vy1 & vx1) ? w11 : 0.0f;

        const float4* p00 = reinterpret_cast<const float4*>(xb + (size_t)(yc0 * W + xc0) * Cpg);
        const float4* p01 = reinterpret_cast<const float4*>(xb + (size_t)(yc0 * W + xc1) * Cpg);
        const float4* p10 = reinterpret_cast<const float4*>(xb + (size_t)(yc1 * W + xc0) * Cpg);
        const float4* p11 = reinterpret_cast<const float4*>(xb + (size_t)(yc1 * W + xc1) * Cpg);

        const float4 a00 = p00[0], b00 = p00[1];
        const float4 a01 = p01[0], b01 = p01[1];
        const float4 a10 = p10[0], b10 = p10[1];
        const float4 a11 = p11[0], b11 = p11[1];

        // s[c] = bilinear blend of 4 corners, channels 0-7
        float s[Cpg];
        s[0] = w00 * a00.x + w01 * a01.x + w10 * a10.x + w11 * a11.x;
        s[1] = w00 * a00.y + w01 * a01.y + w10 * a10.y + w11 * a11.y;
        s[2] = w00 * a00.z + w01 * a01.z + w10 * a10.z + w11 * a11.z;
        s[3] = w00 * a00.w + w01 * a01.w + w10 * a10.w + w11 * a11.w;
        s[4] = w00 * b00.x + w01 * b01.x + w10 * b10.x + w11 * b11.x;
        s[5] = w00 * b00.y + w01 * b01.y + w10 * b10.y + w11 * b11.y;
        s[6] = w00 * b00.z + w01 * b01.z + w10 * b10.z + w11 * b11.z;
        s[7] = w00 * b00.w + w01 * b01.w + w10 * b10.w + w11 * b11.w;

        const float* wt = &wlds[t * Cpg * OPG];
#pragma unroll
        for (int c = 0; c < Cpg; ++c) {
            const float4 wv0 = *reinterpret_cast<const float4*>(&wt[c * OPG]);
            const float4 wv1 = *reinterpret_cast<const float4*>(&wt[c * OPG + 4]);
            acc[0] += s[c] * wv0.x;
            acc[1] += s[c] * wv0.y;
            acc[2] += s[c] * wv0.z;
            acc[3] += s[c] * wv0.w;
            acc[4] += s[c] * wv1.x;
            acc[5] += s[c] * wv1.y;
            acc[6] += s[c] * wv1.z;
            acc[7] += s[c] * wv1.w;
        }
    }

    float* ob = out + (size_t)(b * OC + g * OPG) * HW + pix;
#pragma unroll
    for (int d = 0; d < OPG; ++d) {
        ob[(size_t)d * HW] = acc[d] + bias[g * OPG + d];
    }
}

extern "C" void kernel_launch(void* const* d_in, const int* in_sizes, int n_in,
                              void* d_out, int out_size, void* d_ws, size_t ws_size,
                              hipStream_t stream) {
    const float* x      = (const float*)d_in[0];
    const float* offset = (const float*)d_in[1];
    const float* mask   = (const float*)d_in[2];
    const float* weight = (const float*)d_in[3];
    const float* bias   = (const float*)d_in[4];
    float* out = (float*)d_out;
    float* xt  = (float*)d_ws;   // needs B*Cin*H*W*4 = 64 MiB

    dim3 grid(H, G, B);
    dim3 block(W);
    transpose_kernel<<<grid, block, 0, stream>>>(x, xt);
    dcn_kernel<<<grid, block, 0, stream>>>(xt, offset, mask, weight, bias, out);
}

// Round 3
// 198.117 us; speedup vs baseline: 2.1786x; 1.5815x over previous
//
#include <hip/hip_runtime.h>

// Deformable Conv2d given offsets — MI355X, round 3
// vs round 2: (1) xt stored as bf16 channels-last -> one dwordx4 per bilinear
// corner (half the scattered-load instructions and half the gather bytes);
// (2) XCD-chunked block swizzle so each XCD's private L2 sees contiguous h
// rows of the same (b,g) plane (kills the ~3x xt re-fetch amplification).

#define KSZ 3
#define PAD 1

static constexpr int B   = 4;
static constexpr int Cin = 64;
static constexpr int H   = 256;
static constexpr int W   = 256;
static constexpr int G   = 8;
static constexpr int OC  = 64;
static constexpr int KK  = KSZ * KSZ;      // 9
static constexpr int Cpg = Cin / G;        // 8
static constexpr int OPG = OC / G;         // 8
static constexpr int HW  = H * W;          // 65536
static constexpr int NXCD = 8;

__device__ __forceinline__ unsigned f2bf(float f) {   // RNE f32 -> bf16
    unsigned u = __float_as_uint(f);
    return (u + 0x7fffu + ((u >> 16) & 1u)) >> 16;
}
__device__ __forceinline__ float bflo(unsigned u) { return __uint_as_float(u << 16); }
__device__ __forceinline__ float bfhi(unsigned u) { return __uint_as_float(u & 0xffff0000u); }

__device__ __forceinline__ void unpack8(const uint4 q, float* f) {
    f[0] = bflo(q.x); f[1] = bfhi(q.x);
    f[2] = bflo(q.y); f[3] = bfhi(q.y);
    f[4] = bflo(q.z); f[5] = bfhi(q.z);
    f[6] = bflo(q.w); f[7] = bfhi(q.w);
}

// ---- transpose: x [B,Cin,H,W] f32 -> xt [B,G,H,W,Cpg] bf16 ----
__global__ __launch_bounds__(256) void transpose_kernel(
    const float* __restrict__ x, unsigned* __restrict__ xt)
{
    const int h = blockIdx.x;
    const int g = blockIdx.y;
    const int b = blockIdx.z;
    const int w = threadIdx.x;
    const int pix = h * W + w;

    const float* src = x + (size_t)(b * Cin + g * Cpg) * HW + pix;
    float v[Cpg];
#pragma unroll
    for (int c = 0; c < Cpg; ++c) v[c] = src[(size_t)c * HW];  // coalesced per c

    uint4 pk;
    pk.x = f2bf(v[0]) | (f2bf(v[1]) << 16);
    pk.y = f2bf(v[2]) | (f2bf(v[3]) << 16);
    pk.z = f2bf(v[4]) | (f2bf(v[5]) << 16);
    pk.w = f2bf(v[6]) | (f2bf(v[7]) << 16);

    // 16B contiguous per lane
    uint4* dst = reinterpret_cast<uint4*>(xt + ((size_t)(b * G + g) * HW + pix) * (Cpg / 2));
    *dst = pk;
}

// ---- main kernel ----
__global__ __launch_bounds__(256) void dcn_kernel(
    const unsigned* __restrict__ xt,
    const float* __restrict__ offset,
    const float* __restrict__ mask,
    const float* __restrict__ weight,
    const float* __restrict__ bias,
    float* __restrict__ out)
{
    // XCD-chunked bijective swizzle: 8192 blocks, XCD k gets contiguous
    // work ids [k*1024, (k+1)*1024) in (b,g,h) order.
    const unsigned id = blockIdx.x;
    const unsigned wl = (id & (NXCD - 1)) * (gridDim.x / NXCD) + (id >> 3);
    const int h  = wl & (H - 1);
    const int bg = wl >> 8;
    const int g  = bg & (G - 1);
    const int b  = bg >> 3;
    const int w  = threadIdx.x;

    // Group weights in LDS as [t][c][d]; inner reads are lane-broadcast.
    __shared__ float wlds[KK * Cpg * OPG];
    for (int i = threadIdx.x; i < KK * Cpg * OPG; i += blockDim.x) {
        const int t = i / (Cpg * OPG);
        const int r = i - t * (Cpg * OPG);
        const int c = r / OPG;
        const int d = r - c * OPG;
        wlds[i] = weight[((g * OPG + d) * Cpg + c) * KK + t];
    }
    __syncthreads();

    float acc[OPG];
#pragma unroll
    for (int d = 0; d < OPG; ++d) acc[d] = 0.0f;

    const unsigned* xb = xt + (size_t)(b * G + g) * HW * (Cpg / 2);
    const int pix = h * W + w;

#pragma unroll
    for (int t = 0; t < KK; ++t) {
        const int ki = t / KSZ;
        const int kj = t - ki * KSZ;
        // reference flips the (group,tap) axis: channel 71-(g*9+t)
        const int idx0 = G * KK - 1 - (g * KK + t);
        const float dy = offset[((size_t)(b * 2 + 0) * (G * KK) + idx0) * HW + pix];
        const float dx = offset[((size_t)(b * 2 + 1) * (G * KK) + idx0) * HW + pix];
        const float mv = mask[((size_t)b * (G * KK) + g * KK + t) * HW + pix];
        const float m = 1.0f / (1.0f + __expf(-mv));

        const float py = (float)(h - PAD + ki) + dy;
        const float px = (float)(w - PAD + kj) + dx;
        const float y0f = floorf(py);
        const float x0f = floorf(px);
        const float wy = py - y0f;
        const float wx = px - x0f;
        const int y0 = (int)y0f, x0 = (int)x0f;
        const int y1 = y0 + 1,   x1 = x0 + 1;

        const bool vy0 = (y0 >= 0) & (y0 < H);
        const bool vy1 = (y1 >= 0) & (y1 < H);
        const bool vx0 = (x0 >= 0) & (x0 < W);
        const bool vx1 = (x1 >= 0) & (x1 < W);

        const int yc0 = min(max(y0, 0), H - 1);
        const int yc1 = min(max(y1, 0), H - 1);
        const int xc0 = min(max(x0, 0), W - 1);
        const int xc1 = min(max(x1, 0), W - 1);

        float w00 = (1.0f - wy) * (1.0f - wx) * m;
        float w01 = (1.0f - wy) * wx * m;
        float w10 = wy * (1.0f - wx) * m;
        float w11 = wy * wx * m;
        w00 = (vy0 & vx0) ? w00 : 0.0f;
        w01 = (vy0 & vx1) ? w01 : 0.0f;
        w10 = (vy1 & vx0) ? w10 : 0.0f;
        w11 = (vy1 & vx1) ? w11 : 0.0f;

        // one dwordx4 (8 bf16 channels) per corner
        const uint4 q00 = *reinterpret_cast<const uint4*>(xb + (size_t)(yc0 * W + xc0) * (Cpg / 2));
        const uint4 q01 = *reinterpret_cast<const uint4*>(xb + (size_t)(yc0 * W + xc1) * (Cpg / 2));
        const uint4 q10 = *reinterpret_cast<const uint4*>(xb + (size_t)(yc1 * W + xc0) * (Cpg / 2));
        const uint4 q11 = *reinterpret_cast<const uint4*>(xb + (size_t)(yc1 * W + xc1) * (Cpg / 2));

        float a00[8], a01[8], a10[8], a11[8];
        unpack8(q00, a00);
        unpack8(q01, a01);
        unpack8(q10, a10);
        unpack8(q11, a11);

        const float* wt = &wlds[t * Cpg * OPG];
#pragma unroll
        for (int c = 0; c < Cpg; ++c) {
            const float s = w00 * a00[c] + w01 * a01[c] + w10 * a10[c] + w11 * a11[c];
            const float4 wv0 = *reinterpret_cast<const float4*>(&wt[c * OPG]);
            const float4 wv1 = *reinterpret_cast<const float4*>(&wt[c * OPG + 4]);
            acc[0] += s * wv0.x;
            acc[1] += s * wv0.y;
            acc[2] += s * wv0.z;
            acc[3] += s * wv0.w;
            acc[4] += s * wv1.x;
            acc[5] += s * wv1.y;
            acc[6] += s * wv1.z;
            acc[7] += s * wv1.w;
        }
    }

    float* ob = out + (size_t)(b * OC + g * OPG) * HW + pix;
#pragma unroll
    for (int d = 0; d < OPG; ++d) {
        ob[(size_t)d * HW] = acc[d] + bias[g * OPG + d];
    }
}

extern "C" void kernel_launch(void* const* d_in, const int* in_sizes, int n_in,
                              void* d_out, int out_size, void* d_ws, size_t ws_size,
                              hipStream_t stream) {
    const float* x      = (const float*)d_in[0];
    const float* offset = (const float*)d_in[1];
    const float* mask   = (const float*)d_in[2];
    const float* weight = (const float*)d_in[3];
    const float* bias   = (const float*)d_in[4];
    float* out = (float*)d_out;
    unsigned* xt = (unsigned*)d_ws;   // B*G*HW*Cpg bf16 = 32 MiB

    dim3 tgrid(H, G, B);
    dim3 block(W);
    transpose_kernel<<<tgrid, block, 0, stream>>>(x, xt);
    dcn_kernel<<<dim3(B * G * H), block, 0, stream>>>(xt, offset, mask, weight, bias, out);
}

// Round 4
// 181.902 us; speedup vs baseline: 2.3728x; 1.0891x over previous
//
#include <hip/hip_runtime.h>
#include <hip/hip_fp16.h>

// Deformable Conv2d — MI355X, round 4
// vs round 3: the 8x8 per-tap matmul moves to the matrix pipe via
// mfma_f32_32x32x16_f16 (A = weights [32outs x 16k], B = blended samples
// [16k x 32pix]); xt stored fp16 channels-last and the bilinear blend runs
// in packed v_pk_fma_f16. Kills the 64 VALU-FMA matmul + 16 ds_reads per
// pixel-tap that dominated round 3's VALUBusy.

#define KSZ 3
#define PAD 1

static constexpr int B   = 4;
static constexpr int Cin = 64;
static constexpr int H   = 256;
static constexpr int W   = 256;
static constexpr int G   = 8;
static constexpr int OC  = 64;
static constexpr int KK  = KSZ * KSZ;  // 9
static constexpr int Cpg = Cin / G;    // 8
static constexpr int OPG = OC / G;     // 8
static constexpr int HW  = H * W;
static constexpr int NXCD = 8;

typedef _Float16 f16x8 __attribute__((ext_vector_type(8)));
typedef float    f32x16 __attribute__((ext_vector_type(16)));

union U4H {
    uint4 u;
    __half2 h2[4];
    _Float16 h[8];
    f16x8 v;
};

// ---- transpose: x [B,Cin,H,W] f32 -> xt [B,G,H,W,Cpg] fp16 (16B per pixel) ----
__global__ __launch_bounds__(256) void transpose_kernel(
    const float* __restrict__ x, uint4* __restrict__ xt)
{
    const int h = blockIdx.x, g = blockIdx.y, b = blockIdx.z;
    const int w = threadIdx.x;
    const int pix = h * W + w;
    const float* src = x + (size_t)(b * Cin + g * Cpg) * HW + pix;
    U4H v;
#pragma unroll
    for (int c = 0; c < 8; ++c) v.h[c] = (_Float16)src[(size_t)c * HW];
    xt[(size_t)(b * G + g) * HW + pix] = v.u;
}

// ---- main kernel ----
__global__ __launch_bounds__(256) void dcn_kernel(
    const uint4* __restrict__ xt,
    const float* __restrict__ offset,
    const float* __restrict__ mask,
    const float* __restrict__ weight,
    const float* __restrict__ bias,
    float* __restrict__ out)
{
    // XCD-chunked bijective swizzle (8192 blocks % 8 == 0)
    const unsigned id = blockIdx.x;
    const unsigned wl = (id & (NXCD - 1)) * (gridDim.x / NXCD) + (id >> 3);
    const int h  = wl & (H - 1);
    const int bg = wl >> 8;
    const int g  = bg & (G - 1);
    const int b  = bg >> 3;

    const int lane = threadIdx.x & 63;
    const int wave = threadIdx.x >> 6;
    const int hi   = lane >> 5;   // k-chunk half: tap parity within MFMA
    const int lp   = lane & 31;   // A-row (out) / B-col (pixel)

    // A-fragments: weights. A[row=d][k], lane holds row=lp, k=hi*8+c
    // -> tap t = 2m+hi, channel c = elem j. Rows >=8 and pad tap 9 are zero.
    f16x8 afrag[5];
#pragma unroll
    for (int m = 0; m < 5; ++m) {
        f16x8 a = {};
        const int t = 2 * m + hi;
        if (lp < OPG && t < KK) {
            const float* wp = weight + (size_t)(g * OPG + lp) * Cpg * KK + t;
#pragma unroll
            for (int c = 0; c < 8; ++c) a[c] = (_Float16)wp[c * KK];
        }
        afrag[m] = a;
    }

    const uint4* xb  = xt + (size_t)(b * G + g) * HW;
    const float* offy = offset + (size_t)(b * 2 + 0) * (G * KK) * HW;
    const float* offx = offset + (size_t)(b * 2 + 1) * (G * KK) * HW;
    const float* mk   = mask + (size_t)b * (G * KK) * HW;

    f32x16 acc0 = {};
    f32x16 acc1 = {};

#pragma unroll
    for (int tile = 0; tile < 2; ++tile) {
        const int wq  = wave * 64 + tile * 32 + lp;  // w coordinate
        const int pix = h * W + wq;
#pragma unroll
        for (int m = 0; m < 5; ++m) {
            const int t = 2 * m + hi;
            f16x8 bfrag = {};
            if (t < KK) {
                const int ki = t / 3, kj = t - 3 * (t / 3);
                const int idx0 = G * KK - 1 - (g * KK + t);   // offset axis flipped
                const float dy = offy[(size_t)idx0 * HW + pix];
                const float dx = offx[(size_t)idx0 * HW + pix];
                const float mv = mk[(size_t)(g * KK + t) * HW + pix];
                const float msig = 1.0f / (1.0f + __expf(-mv));

                const float py = (float)(h - PAD + ki) + dy;
                const float px = (float)(wq - PAD + kj) + dx;
                const float y0f = floorf(py), x0f = floorf(px);
                const float wy = py - y0f, wx = px - x0f;
                const int y0 = (int)y0f, x0 = (int)x0f;
                const int y1 = y0 + 1,   x1 = x0 + 1;
                const bool vy0 = (y0 >= 0) & (y0 < H), vy1 = (y1 >= 0) & (y1 < H);
                const bool vx0 = (x0 >= 0) & (x0 < W), vx1 = (x1 >= 0) & (x1 < W);
                const int yc0 = min(max(y0, 0), H - 1), yc1 = min(max(y1, 0), H - 1);
                const int xc0 = min(max(x0, 0), W - 1), xc1 = min(max(x1, 0), W - 1);

                float w00 = (1.f - wy) * (1.f - wx) * msig;
                float w01 = (1.f - wy) * wx * msig;
                float w10 = wy * (1.f - wx) * msig;
                float w11 = wy * wx * msig;
                w00 = (vy0 & vx0) ? w00 : 0.f;
                w01 = (vy0 & vx1) ? w01 : 0.f;
                w10 = (vy1 & vx0) ? w10 : 0.f;
                w11 = (vy1 & vx1) ? w11 : 0.f;

                U4H q00, q01, q10, q11;
                q00.u = xb[yc0 * W + xc0];
                q01.u = xb[yc0 * W + xc1];
                q10.u = xb[yc1 * W + xc0];
                q11.u = xb[yc1 * W + xc1];

                const __half2 hw00 = __float2half2_rn(w00);
                const __half2 hw01 = __float2half2_rn(w01);
                const __half2 hw10 = __float2half2_rn(w10);
                const __half2 hw11 = __float2half2_rn(w11);

                U4H s;
#pragma unroll
                for (int i = 0; i < 4; ++i)
                    s.h2[i] = __hfma2(hw00, q00.h2[i],
                              __hfma2(hw01, q01.h2[i],
                              __hfma2(hw10, q10.h2[i],
                              __hmul2(hw11, q11.h2[i]))));
                bfrag = s.v;
            }
            if (tile == 0)
                acc0 = __builtin_amdgcn_mfma_f32_32x32x16_f16(afrag[m], bfrag, acc0, 0, 0, 0);
            else
                acc1 = __builtin_amdgcn_mfma_f32_32x32x16_f16(afrag[m], bfrag, acc1, 0, 0, 0);
        }
    }

    // C layout: col = lp (pixel), row = (reg&3) + 8*(reg>>2) + 4*hi.
    // Useful: regs 0..3 -> out channel d = reg + 4*hi (rows >=8 are zero).
#pragma unroll
    for (int tile = 0; tile < 2; ++tile) {
        const int wq = wave * 64 + tile * 32 + lp;
#pragma unroll
        for (int r = 0; r < 4; ++r) {
            const int dd = r + 4 * hi;
            const float v = (tile == 0 ? acc0[r] : acc1[r]) + bias[g * OPG + dd];
            out[((size_t)b * OC + g * OPG + dd) * HW + h * W + wq] = v;
        }
    }
}

extern "C" void kernel_launch(void* const* d_in, const int* in_sizes, int n_in,
                              void* d_out, int out_size, void* d_ws, size_t ws_size,
                              hipStream_t stream) {
    const float* x      = (const float*)d_in[0];
    const float* offset = (const float*)d_in[1];
    const float* mask   = (const float*)d_in[2];
    const float* weight = (const float*)d_in[3];
    const float* bias   = (const float*)d_in[4];
    float* out = (float*)d_out;
    uint4* xt  = (uint4*)d_ws;   // B*G*HW * 16B = 32 MiB

    dim3 tgrid(H, G, B);
    dim3 block(W);
    transpose_kernel<<<tgrid, block, 0, stream>>>(x, xt);
    dcn_kernel<<<dim3(B * G * H), block, 0, stream>>>(xt, offset, mask, weight, bias, out);
}

// Round 5
// 179.641 us; speedup vs baseline: 2.4027x; 1.0126x over previous
//
#include <hip/hip_runtime.h>
#include <hip/hip_fp16.h>

// Deformable Conv2d — MI355X, round 5
// vs round 4: explicit software pipeline. All 30 offset/mask loads burst up
// front; corner gathers for tap m+1 issue before the blend of tap m (8
// scattered dwordx4 in flight per wave, steady state); branchless tap-9 pad;
// __launch_bounds__(256,4) so the allocator stops squeezing to 44 VGPR.

#define KSZ 3
#define PAD 1

static constexpr int B   = 4;
static constexpr int Cin = 64;
static constexpr int H   = 256;
static constexpr int W   = 256;
static constexpr int G   = 8;
static constexpr int OC  = 64;
static constexpr int KK  = KSZ * KSZ;  // 9
static constexpr int Cpg = Cin / G;    // 8
static constexpr int OPG = OC / G;     // 8
static constexpr int HW  = H * W;
static constexpr int NXCD = 8;

typedef _Float16 f16x8  __attribute__((ext_vector_type(8)));
typedef float    f32x16 __attribute__((ext_vector_type(16)));

union U4H {
    uint4 u;
    __half2 h2[4];
    _Float16 h[8];
    f16x8 v;
};

struct TapP { float w00, w01, w10, w11; int o00, o01, o10, o11; };

// ---- transpose: x [B,Cin,H,W] f32 -> xt [B,G,H,W,Cpg] fp16 (16B/pixel) ----
__global__ __launch_bounds__(256) void transpose_kernel(
    const float* __restrict__ x, uint4* __restrict__ xt)
{
    const int h = blockIdx.x, g = blockIdx.y, b = blockIdx.z;
    const int w = threadIdx.x;
    const int pix = h * W + w;
    const float* src = x + (size_t)(b * Cin + g * Cpg) * HW + pix;
    U4H v;
#pragma unroll
    for (int c = 0; c < 8; ++c) v.h[c] = (_Float16)src[(size_t)c * HW];
    xt[(size_t)(b * G + g) * HW + pix] = v.u;
}

// per-tap bilinear weights (validity + sigmoid(mask) + tap-9 pad folded in)
// and the 4 corner pixel offsets.
__device__ __forceinline__ TapP tap_params(int t, int h, int wq,
                                           float dy, float dx, float mv)
{
    const int tt = (t > 8) ? 8 : t;
    const int ki = (tt >= 3) + (tt >= 6);
    const int kj = tt - 3 * ki;
    float msig = 1.0f / (1.0f + __expf(-mv));
    msig = (t <= 8) ? msig : 0.0f;          // pad tap contributes nothing

    const float py = (float)(h - PAD + ki) + dy;
    const float px = (float)(wq - PAD + kj) + dx;
    const float y0f = floorf(py), x0f = floorf(px);
    const float wy = py - y0f, wx = px - x0f;
    const int y0 = (int)y0f, x0 = (int)x0f;
    const int y1 = y0 + 1,   x1 = x0 + 1;
    const bool vy0 = (y0 >= 0) & (y0 < H), vy1 = (y1 >= 0) & (y1 < H);
    const bool vx0 = (x0 >= 0) & (x0 < W), vx1 = (x1 >= 0) & (x1 < W);
    const int yc0 = min(max(y0, 0), H - 1), yc1 = min(max(y1, 0), H - 1);
    const int xc0 = min(max(x0, 0), W - 1), xc1 = min(max(x1, 0), W - 1);

    TapP p;
    p.w00 = (vy0 & vx0) ? (1.f - wy) * (1.f - wx) * msig : 0.f;
    p.w01 = (vy0 & vx1) ? (1.f - wy) * wx * msig : 0.f;
    p.w10 = (vy1 & vx0) ? wy * (1.f - wx) * msig : 0.f;
    p.w11 = (vy1 & vx1) ? wy * wx * msig : 0.f;
    p.o00 = yc0 * W + xc0;  p.o01 = yc0 * W + xc1;
    p.o10 = yc1 * W + xc0;  p.o11 = yc1 * W + xc1;
    return p;
}

__device__ __forceinline__ f16x8 blend(const TapP& p, uint4 u00, uint4 u01,
                                       uint4 u10, uint4 u11)
{
    U4H a, bq, c, d; a.u = u00; bq.u = u01; c.u = u10; d.u = u11;
    const __half2 hw00 = __float2half2_rn(p.w00);
    const __half2 hw01 = __float2half2_rn(p.w01);
    const __half2 hw10 = __float2half2_rn(p.w10);
    const __half2 hw11 = __float2half2_rn(p.w11);
    U4H s;
#pragma unroll
    for (int i = 0; i < 4; ++i)
        s.h2[i] = __hfma2(hw00, a.h2[i],
                  __hfma2(hw01, bq.h2[i],
                  __hfma2(hw10, c.h2[i],
                  __hmul2(hw11, d.h2[i]))));
    return s.v;
}

// one tile = 32 pixels, 5 MFMA stages, depth-2 gather pipeline
#define TILE_PIPE(TILE, ACC)                                                           \
  {                                                                                    \
    const int wq_ = wave * 64 + (TILE) * 32 + lp;                                      \
    TapP p0 = tap_params(0 + hi, h, wq_, dyv[TILE][0], dxv[TILE][0], mvv[TILE][0]);    \
    uint4 a0 = xb[p0.o00], a1 = xb[p0.o01], a2 = xb[p0.o10], a3 = xb[p0.o11];          \
    TapP p1 = tap_params(2 + hi, h, wq_, dyv[TILE][1], dxv[TILE][1], mvv[TILE][1]);    \
    uint4 b0 = xb[p1.o00], b1 = xb[p1.o01], b2 = xb[p1.o10], b3 = xb[p1.o11];          \
    ACC = __builtin_amdgcn_mfma_f32_32x32x16_f16(afrag[0], blend(p0,a0,a1,a2,a3), ACC,0,0,0); \
    TapP p2 = tap_params(4 + hi, h, wq_, dyv[TILE][2], dxv[TILE][2], mvv[TILE][2]);    \
    uint4 c0 = xb[p2.o00], c1 = xb[p2.o01], c2 = xb[p2.o10], c3 = xb[p2.o11];          \
    ACC = __builtin_amdgcn_mfma_f32_32x32x16_f16(afrag[1], blend(p1,b0,b1,b2,b3), ACC,0,0,0); \
    TapP p3 = tap_params(6 + hi, h, wq_, dyv[TILE][3], dxv[TILE][3], mvv[TILE][3]);    \
    uint4 d0 = xb[p3.o00], d1 = xb[p3.o01], d2 = xb[p3.o10], d3 = xb[p3.o11];          \
    ACC = __builtin_amdgcn_mfma_f32_32x32x16_f16(afrag[2], blend(p2,c0,c1,c2,c3), ACC,0,0,0); \
    TapP p4 = tap_params(8 + hi, h, wq_, dyv[TILE][4], dxv[TILE][4], mvv[TILE][4]);    \
    uint4 e0 = xb[p4.o00], e1 = xb[p4.o01], e2 = xb[p4.o10], e3 = xb[p4.o11];          \
    ACC = __builtin_amdgcn_mfma_f32_32x32x16_f16(afrag[3], blend(p3,d0,d1,d2,d3), ACC,0,0,0); \
    ACC = __builtin_amdgcn_mfma_f32_32x32x16_f16(afrag[4], blend(p4,e0,e1,e2,e3), ACC,0,0,0); \
  }

__global__ __launch_bounds__(256, 4) void dcn_kernel(
    const uint4* __restrict__ xt,
    const float* __restrict__ offset,
    const float* __restrict__ mask,
    const float* __restrict__ weight,
    const float* __restrict__ bias,
    float* __restrict__ out)
{
    // XCD-chunked bijective swizzle (8192 blocks % 8 == 0)
    const unsigned id = blockIdx.x;
    const unsigned wl = (id & (NXCD - 1)) * (gridDim.x / NXCD) + (id >> 3);
    const int h  = wl & (H - 1);
    const int bg = wl >> 8;
    const int g  = bg & (G - 1);
    const int b  = bg >> 3;

    const int lane = threadIdx.x & 63;
    const int wave = threadIdx.x >> 6;
    const int hi   = lane >> 5;   // tap parity within the MFMA k dimension
    const int lp   = lane & 31;   // A-row (out ch) / B-col (pixel)

    // A-fragments: weights, A[row=d][k=hi*8+c] -> tap 2m+hi, channel c.
    f16x8 afrag[5];
#pragma unroll
    for (int m = 0; m < 5; ++m) {
        f16x8 a = {};
        const int t = 2 * m + hi;
        if (lp < OPG && t < KK) {
            const float* wp = weight + (size_t)(g * OPG + lp) * Cpg * KK + t;
#pragma unroll
            for (int c = 0; c < 8; ++c) a[c] = (_Float16)wp[c * KK];
        }
        afrag[m] = a;
    }

    const uint4* xb   = xt + (size_t)(b * G + g) * HW;
    const float* offy = offset + (size_t)(b * 2 + 0) * (G * KK) * HW;
    const float* offx = offset + (size_t)(b * 2 + 1) * (G * KK) * HW;
    const float* mk   = mask + (size_t)b * (G * KK) * HW;

    // burst all 30 offset/mask loads up front (coalesced; latency paid once)
    float dyv[2][5], dxv[2][5], mvv[2][5];
#pragma unroll
    for (int tile = 0; tile < 2; ++tile) {
        const int wq  = wave * 64 + tile * 32 + lp;
        const int pix = h * W + wq;
#pragma unroll
        for (int m = 0; m < 5; ++m) {
            const int t  = 2 * m + hi;
            const int tt = (t > 8) ? 8 : t;
            const int idx0 = G * KK - 1 - (g * KK + tt);   // flipped tap axis
            dyv[tile][m] = offy[(size_t)idx0 * HW + pix];
            dxv[tile][m] = offx[(size_t)idx0 * HW + pix];
            mvv[tile][m] = mk[(size_t)(g * KK + tt) * HW + pix];
        }
    }

    f32x16 acc0 = {};
    f32x16 acc1 = {};
    TILE_PIPE(0, acc0)
    TILE_PIPE(1, acc1)

    // C layout: col = lp (pixel), row = (reg&3) + 8*(reg>>2) + 4*hi.
    // Useful rows 0..7 -> out channel d = reg + 4*hi (regs 0..3).
#pragma unroll
    for (int tile = 0; tile < 2; ++tile) {
        const int wq = wave * 64 + tile * 32 + lp;
#pragma unroll
        for (int r = 0; r < 4; ++r) {
            const int dd = r + 4 * hi;
            const float v = (tile == 0 ? acc0[r] : acc1[r]) + bias[g * OPG + dd];
            out[((size_t)b * OC + g * OPG + dd) * HW + h * W + wq] = v;
        }
    }
}

extern "C" void kernel_launch(void* const* d_in, const int* in_sizes, int n_in,
                              void* d_out, int out_size, void* d_ws, size_t ws_size,
                              hipStream_t stream) {
    const float* x      = (const float*)d_in[0];
    const float* offset = (const float*)d_in[1];
    const float* mask   = (const float*)d_in[2];
    const float* weight = (const float*)d_in[3];
    const float* bias   = (const float*)d_in[4];
    float* out = (float*)d_out;
    uint4* xt  = (uint4*)d_ws;   // B*G*HW * 16B = 32 MiB

    dim3 tgrid(H, G, B);
    dim3 block(W);
    transpose_kernel<<<tgrid, block, 0, stream>>>(x, xt);
    dcn_kernel<<<dim3(B * G * H), block, 0, stream>>>(xt, offset, mask, weight, bias, out);
}

// Round 6
// 114.173 us; speedup vs baseline: 3.7804x; 1.5734x over previous
//
#include <hip/hip_runtime.h>
#include <hip/hip_fp16.h>

// Deformable Conv2d — MI355X, round 6
// vs round 5: corner gathers moved from global (L1/TA-throughput bound at
// ~40 line-touches per wave-instruction) to an LDS window. Each block stages
// rows h-5..h+6 of its (b,g) fp16 plane (49.3 KB, pitch 257 slots to dodge
// bank aliasing); gathers become ds_read_b128. Out-of-window rows (|dy|>4-5,
// p~1e-4) fall back to global via a __any-guarded branch.

#define KSZ 3
#define PAD 1

static constexpr int B   = 4;
static constexpr int Cin = 64;
static constexpr int H   = 256;
static constexpr int W   = 256;
static constexpr int G   = 8;
static constexpr int OC  = 64;
static constexpr int KK  = KSZ * KSZ;  // 9
static constexpr int Cpg = Cin / G;    // 8
static constexpr int OPG = OC / G;     // 8
static constexpr int HW  = H * W;
static constexpr int NXCD = 8;

static constexpr int WROWS = 12;       // window rows: h-5 .. h+6
static constexpr int WUP   = 5;        // rows above h
static constexpr int WPITCH = 257;     // 16B slots per row (257*16B: stride % 32 banks != 0)

typedef _Float16 f16x8  __attribute__((ext_vector_type(8)));
typedef float    f32x16 __attribute__((ext_vector_type(16)));

union U4H {
    uint4 u;
    __half2 h2[4];
    _Float16 h[8];
    f16x8 v;
};

// ---- transpose: x [B,Cin,H,W] f32 -> xt [B,G,H,W,Cpg] fp16 (16B/pixel) ----
__global__ __launch_bounds__(256) void transpose_kernel(
    const float* __restrict__ x, uint4* __restrict__ xt)
{
    const int h = blockIdx.x, g = blockIdx.y, b = blockIdx.z;
    const int w = threadIdx.x;
    const int pix = h * W + w;
    const float* src = x + (size_t)(b * Cin + g * Cpg) * HW + pix;
    U4H v;
#pragma unroll
    for (int c = 0; c < 8; ++c) v.h[c] = (_Float16)src[(size_t)c * HW];
    xt[(size_t)(b * G + g) * HW + pix] = v.u;
}

// ---- main kernel ----
__global__ __launch_bounds__(256, 3) void dcn_kernel(
    const uint4* __restrict__ xt,
    const float* __restrict__ offset,
    const float* __restrict__ mask,
    const float* __restrict__ weight,
    const float* __restrict__ bias,
    float* __restrict__ out)
{
    __shared__ uint4 win[WROWS * WPITCH];   // 49,344 B

    // XCD-chunked bijective swizzle (8192 blocks % 8 == 0)
    const unsigned id = blockIdx.x;
    const unsigned wl = (id & (NXCD - 1)) * (gridDim.x / NXCD) + (id >> 3);
    const int h  = wl & (H - 1);
    const int bg = wl >> 8;
    const int g  = bg & (G - 1);
    const int b  = bg >> 3;

    const int tid  = threadIdx.x;
    const int lane = tid & 63;
    const int wave = tid >> 6;
    const int hi   = lane >> 5;   // tap parity within the MFMA k dimension
    const int lp   = lane & 31;   // A-row (out ch) / B-col (pixel)

    const uint4* xb = xt + (size_t)(b * G + g) * HW;
    const int h0 = h - WUP;

    // ---- stage the 12-row window (each thread: one pixel column per row) ----
#pragma unroll
    for (int i = 0; i < WROWS; ++i) {
        const int wr = min(max(h0 + i, 0), H - 1);
        win[i * WPITCH + tid] = xb[wr * W + tid];
    }

    // A-fragments: weights, A[row=d][k=hi*8+c] -> tap 2m+hi, channel c.
    f16x8 afrag[5];
#pragma unroll
    for (int m = 0; m < 5; ++m) {
        f16x8 a = {};
        const int t = 2 * m + hi;
        if (lp < OPG && t < KK) {
            const float* wp = weight + (size_t)(g * OPG + lp) * Cpg * KK + t;
#pragma unroll
            for (int c = 0; c < 8; ++c) a[c] = (_Float16)wp[c * KK];
        }
        afrag[m] = a;
    }

    const float* offy = offset + (size_t)(b * 2 + 0) * (G * KK) * HW;
    const float* offx = offset + (size_t)(b * 2 + 1) * (G * KK) * HW;
    const float* mk   = mask + (size_t)b * (G * KK) * HW;

    // burst all 30 offset/mask loads up front (coalesced)
    float dyv[2][5], dxv[2][5], mvv[2][5];
#pragma unroll
    for (int tile = 0; tile < 2; ++tile) {
        const int wq  = wave * 64 + tile * 32 + lp;
        const int pix = h * W + wq;
#pragma unroll
        for (int m = 0; m < 5; ++m) {
            const int t  = 2 * m + hi;
            const int tt = (t > 8) ? 8 : t;
            const int idx0 = G * KK - 1 - (g * KK + tt);   // flipped tap axis
            dyv[tile][m] = offy[(size_t)idx0 * HW + pix];
            dxv[tile][m] = offx[(size_t)idx0 * HW + pix];
            mvv[tile][m] = mk[(size_t)(g * KK + tt) * HW + pix];
        }
    }

    __syncthreads();   // window ready

    // sample one tap: bilinear blend of 4 corners from the LDS window
    auto sample = [&](int t, int wq, float dy, float dx, float mv) -> f16x8 {
        const int tt = (t > 8) ? 8 : t;
        const int ki = (tt >= 3) + (tt >= 6);
        const int kj = tt - 3 * ki;
        float msig = 1.0f / (1.0f + __expf(-mv));
        msig = (t <= 8) ? msig : 0.0f;          // pad tap contributes nothing

        const float py = (float)(h - PAD + ki) + dy;
        const float px = (float)(wq - PAD + kj) + dx;
        const float y0f = floorf(py), x0f = floorf(px);
        const float wy = py - y0f, wx = px - x0f;
        const int y0 = (int)y0f, x0 = (int)x0f;
        const int y1 = y0 + 1,   x1 = x0 + 1;
        const bool vy0 = (y0 >= 0) & (y0 < H), vy1 = (y1 >= 0) & (y1 < H);
        const bool vx0 = (x0 >= 0) & (x0 < W), vx1 = (x1 >= 0) & (x1 < W);
        const int yc0 = min(max(y0, 0), H - 1), yc1 = min(max(y1, 0), H - 1);
        const int xc0 = min(max(x0, 0), W - 1), xc1 = min(max(x1, 0), W - 1);

        float w00 = (vy0 & vx0) ? (1.f - wy) * (1.f - wx) * msig : 0.f;
        float w01 = (vy0 & vx1) ? (1.f - wy) * wx * msig : 0.f;
        float w10 = (vy1 & vx0) ? wy * (1.f - wx) * msig : 0.f;
        float w11 = (vy1 & vx1) ? wy * wx * msig : 0.f;

        const int iy0 = yc0 - h0, iy1 = yc1 - h0;
        const int i0 = min(max(iy0, 0), WROWS - 1);
        const int i1 = min(max(iy1, 0), WROWS - 1);

        uint4 v00 = win[i0 * WPITCH + xc0];
        uint4 v01 = win[i0 * WPITCH + xc1];
        uint4 v10 = win[i1 * WPITCH + xc0];
        uint4 v11 = win[i1 * WPITCH + xc1];

        const bool bad = ((unsigned)iy0 > (unsigned)(WROWS - 1)) |
                         ((unsigned)iy1 > (unsigned)(WROWS - 1));
        if (__builtin_expect(__any((int)bad), 0)) {   // rare: |offset| > ~4.5
            if (bad) {
                v00 = xb[yc0 * W + xc0];
                v01 = xb[yc0 * W + xc1];
                v10 = xb[yc1 * W + xc0];
                v11 = xb[yc1 * W + xc1];
            }
        }

        U4H a, bq, c, d; a.u = v00; bq.u = v01; c.u = v10; d.u = v11;
        const __half2 hw00 = __float2half2_rn(w00);
        const __half2 hw01 = __float2half2_rn(w01);
        const __half2 hw10 = __float2half2_rn(w10);
        const __half2 hw11 = __float2half2_rn(w11);
        U4H s;
#pragma unroll
        for (int i = 0; i < 4; ++i)
            s.h2[i] = __hfma2(hw00, a.h2[i],
                      __hfma2(hw01, bq.h2[i],
                      __hfma2(hw10, c.h2[i],
                      __hmul2(hw11, d.h2[i]))));
        return s.v;
    };

    f32x16 acc0 = {};
    f32x16 acc1 = {};
    {
        const int wq = wave * 64 + lp;
#pragma unroll
        for (int m = 0; m < 5; ++m)
            acc0 = __builtin_amdgcn_mfma_f32_32x32x16_f16(
                afrag[m], sample(2 * m + hi, wq, dyv[0][m], dxv[0][m], mvv[0][m]), acc0, 0, 0, 0);
    }
    {
        const int wq = wave * 64 + 32 + lp;
#pragma unroll
        for (int m = 0; m < 5; ++m)
            acc1 = __builtin_amdgcn_mfma_f32_32x32x16_f16(
                afrag[m], sample(2 * m + hi, wq, dyv[1][m], dxv[1][m], mvv[1][m]), acc1, 0, 0, 0);
    }

    // C layout: col = lp (pixel), row = (reg&3) + 8*(reg>>2) + 4*hi.
    // Useful rows 0..7 -> out channel d = reg + 4*hi (regs 0..3).
#pragma unroll
    for (int tile = 0; tile < 2; ++tile) {
        const int wq = wave * 64 + tile * 32 + lp;
#pragma unroll
        for (int r = 0; r < 4; ++r) {
            const int dd = r + 4 * hi;
            const float v = (tile == 0 ? acc0[r] : acc1[r]) + bias[g * OPG + dd];
            out[((size_t)b * OC + g * OPG + dd) * HW + h * W + wq] = v;
        }
    }
}

extern "C" void kernel_launch(void* const* d_in, const int* in_sizes, int n_in,
                              void* d_out, int out_size, void* d_ws, size_t ws_size,
                              hipStream_t stream) {
    const float* x      = (const float*)d_in[0];
    const float* offset = (const float*)d_in[1];
    const float* mask   = (const float*)d_in[2];
    const float* weight = (const float*)d_in[3];
    const float* bias   = (const float*)d_in[4];
    float* out = (float*)d_out;
    uint4* xt  = (uint4*)d_ws;   // B*G*HW * 16B = 32 MiB

    dim3 tgrid(H, G, B);
    dim3 block(W);
    transpose_kernel<<<tgrid, block, 0, stream>>>(x, xt);
    dcn_kernel<<<dim3(B * G * H), block, 0, stream>>>(xt, offset, mask, weight, bias, out);
}